// Round 13
// baseline (121.569 us; speedup 1.0000x reference)
//
#include <hip/hip_runtime.h>
#include <hip/hip_bf16.h>

#define SEQ    4096
#define CDIM   512
#define NHEADS 8
#define HDIM   64
// fold softmax scale and log2(e) into Q once: exp(s*SCALE) == exp2(s')
#define QSCALE 0.18033688f   // 0.125 * 1.4426950408889634

typedef __attribute__((ext_vector_type(4)))  float f32x4;
typedef __attribute__((ext_vector_type(16))) float f32x16;
typedef __attribute__((ext_vector_type(8)))  short bf16x8;

// LDS swizzle for tiles with 64-bf16 (128B) row stride: spread rows across banks.
__device__ __forceinline__ int swz(int row, int col) {
    int b = (row << 7) + (col << 1);
    b ^= (row & 7) << 4;
    return b >> 1;
}

__device__ __forceinline__ short f2bf(float f) {
    union { __hip_bfloat16 h; short s; } u;
    u.h = __float2bfloat16(f);
    return u.s;
}

// async global->LDS, 16B per lane; LDS dest = wave-uniform base + lane*16
__device__ __forceinline__ void gl16(const void* g, void* l) {
    __builtin_amdgcn_global_load_lds(
        (const __attribute__((address_space(1))) unsigned int*)g,
        (__attribute__((address_space(3))) unsigned int*)l,
        16, 0, 0);
}

// ---------------- f32 -> bf16 pre-pass for all three arrays (one launch)
__global__ __launch_bounds__(256) void cvt3_k(
    const float* __restrict__ a0, short* __restrict__ o0, int c0,
    const float* __restrict__ a1, short* __restrict__ o1, int c1,
    const float* __restrict__ a2, short* __restrict__ o2, int c2)
{
    const int total = c0 + c1 + c2;
    int i = blockIdx.x * 256 + threadIdx.x;
    const int stride = gridDim.x * 256;
    for (; i < total; i += stride) {
        const float* a; short* o; int j;
        if (i < c0)           { a = a0; o = o0; j = i; }
        else if (i < c0 + c1) { a = a1; o = o1; j = i - c0; }
        else                  { a = a2; o = o2; j = i - c0 - c1; }
        float4 v = ((const float4*)a)[j];
        short4 r;
        r.x = f2bf(v.x); r.y = f2bf(v.y); r.z = f2bf(v.z); r.w = f2bf(v.w);
        ((short4*)o)[j] = r;
    }
}

// ---------------- QKV GEMM (bf16 inputs): xb[8192,512] @ wb[1536,512]^T
__global__ __launch_bounds__(256) void qkv_gemm_k(
    const short* __restrict__ xb, const short* __restrict__ wb,
    short* __restrict__ qb, short* __restrict__ kb, short* __restrict__ vtb)
{
    __shared__ alignas(16) short As[2][128 * 64];
    __shared__ alignas(16) short Bs[2][128 * 64];
    const int tid  = threadIdx.x;
    const int lane = tid & 63;
    const int l15  = lane & 15;
    const int lg   = lane >> 4;
    const int wv   = tid >> 6;
    const int wy   = wv >> 1, wx = wv & 1;
    const int m0 = blockIdx.x * 128;
    const int n0 = blockIdx.y * 128;

    const f32x4 fzero = {0.f, 0.f, 0.f, 0.f};
    f32x4 acc[4][4];
    #pragma unroll
    for (int i = 0; i < 4; ++i)
        #pragma unroll
        for (int j = 0; j < 4; ++j)
            acc[i][j] = fzero;

    const int row0 = wv * 8 + (lane >> 3);
    const int cb   = ((lane & 7) ^ (lane >> 3)) << 4;
    const char* agp = (const char*)xb + (size_t)(m0 + row0) * 1024 + cb;
    const char* bgp = (const char*)wb + (size_t)(n0 + row0) * 1024 + cb;
    char* al0 = (char*)&As[0][0] + wv * 1024;
    char* al1 = (char*)&As[1][0] + wv * 1024;
    char* bl0 = (char*)&Bs[0][0] + wv * 1024;
    char* bl1 = (char*)&Bs[1][0] + wv * 1024;

    #define QSTAGE(al, bl, kofs) do {                                  \
        _Pragma("unroll")                                              \
        for (int i_ = 0; i_ < 4; ++i_) {                               \
            gl16(agp + (kofs) + i_ * 32768, (al) + i_ * 4096);         \
            gl16(bgp + (kofs) + i_ * 32768, (bl) + i_ * 4096);         \
        } } while (0)

    QSTAGE(al0, bl0, 0);

    int cur = 0;
    for (int k0 = 0; k0 < CDIM; k0 += 64) {
        asm volatile("s_waitcnt vmcnt(0)" ::: "memory");
        __syncthreads();
        if (k0 + 64 < CDIM) {
            if (cur == 0) QSTAGE(al1, bl1, (k0 + 64) * 2);
            else          QSTAGE(al0, bl0, (k0 + 64) * 2);
        }
        const short* Ac = cur ? &As[1][0] : &As[0][0];
        const short* Bc = cur ? &Bs[1][0] : &Bs[0][0];

        #pragma unroll
        for (int ks = 0; ks < 2; ++ks) {
            bf16x8 afr[4], bfr[4];
            #pragma unroll
            for (int i = 0; i < 4; ++i) {
                afr[i] = *(const bf16x8*)(&Ac[swz(wy * 64 + i * 16 + l15, ks * 32 + lg * 8)]);
                bfr[i] = *(const bf16x8*)(&Bc[swz(wx * 64 + i * 16 + l15, ks * 32 + lg * 8)]);
            }
            #pragma unroll
            for (int i = 0; i < 4; ++i)
                #pragma unroll
                for (int j = 0; j < 4; ++j)
                    acc[i][j] = __builtin_amdgcn_mfma_f32_16x16x32_bf16(afr[i], bfr[j], acc[i][j], 0, 0, 0);
        }
        cur ^= 1;
    }
    #undef QSTAGE

    // epilogue: Q (scaled), K as [bh][n][64]; V^T blocked with col-perm (bits 2<->3)
    #pragma unroll
    for (int j = 0; j < 4; ++j) {
        const int d = n0 + wx * 64 + j * 16 + l15;
        const int s = d >> 9;
        const int h = (d >> 6) & 7;
        const int e = d & 63;
        #pragma unroll
        for (int i = 0; i < 4; ++i) {
            #pragma unroll
            for (int r = 0; r < 4; ++r) {
                const int m  = m0 + wy * 64 + i * 16 + lg * 4 + r;
                const int bb = m >> 12;
                const int n  = m & (SEQ - 1);
                const int bh = bb * NHEADS + h;
                const float v = acc[i][j][r];
                if (s == 0) {
                    qb[(((size_t)bh * SEQ + n) << 6) + e] = f2bf(v * QSCALE);
                } else if (s == 1) {
                    kb[(((size_t)bh * SEQ + n) << 6) + e] = f2bf(v);
                } else {
                    // permute within-64 kv index for 32x32 PV fragments: swap bits 2<->3
                    const int c  = n & 63;
                    const int cp = (c & 0x33) | ((c & 0x04) << 1) | ((c & 0x08) >> 1);
                    vtb[((size_t)bh << 18) + ((size_t)(n >> 6) << 12) + (e << 6) + cp] = f2bf(v);
                }
            }
        }
    }
}

// ---------------- Flash attention v9: 32x32x16 MFMA core.
//   Split-KV (2 wave-groups), fixed-base softmax, l via VALU adds,
//   K dbuf / V tribuf rotation, fused QK->exp2 with PV(prev) interleave.
__global__ __launch_bounds__(512) void attn_k(
    const short* __restrict__ qb, const short* __restrict__ kb, const short* __restrict__ vtb,
    short* __restrict__ ob)
{
    __shared__ alignas(16) char smem[81920];
    const int tid  = threadIdx.x;
    const int lane = tid & 63;
    const int l31  = lane & 31;
    const int h8   = (lane >> 5) << 3;   // k-half offset in elements
    const int wv   = (tid >> 6) & 3;     // wave within group
    const int wg   = tid >> 8;           // wave group = kv half
    const int lin  = blockIdx.x;
    const int bh   = lin & 15;
    const int q0   = (lin >> 4) << 7;    // 128 q-rows per block
    const int b    = bh >> 3, h = bh & 7;
    const size_t base = (size_t)bh * SEQ * HDIM;

    // Q fragments (B-operand): lane holds q = l31, d = m*16 + h8 + e, m=0..3
    bf16x8 qf0, qf1, qf2, qf3;
    {
        const short* qp = qb + base + (size_t)(q0 + wv * 32 + l31) * HDIM + h8;
        qf0 = *(const bf16x8*)(qp);
        qf1 = *(const bf16x8*)(qp + 16);
        qf2 = *(const bf16x8*)(qp + 32);
        qf3 = *(const bf16x8*)(qp + 48);
    }

    f32x16 accA, accB;   // O[q][d 0..31], O[q][d 32..63]
    #pragma unroll
    for (int z = 0; z < 16; ++z) { accA[z] = 0.f; accB[z] = 0.f; }
    float lsum = 0.f;    // partial row sum for (q=l31, kv-half h8)

    // staging: per-group 8KB K dbuf x2 + 8KB V x3; slot t = wv*128 + i*64 + lane
    const int t0  = wv * 128 + lane;
    const int cbs = ((t0 & 7) ^ ((t0 >> 3) & 7)) << 4;
    const int ghb = wg * 262144;   // group's kv-half byte offset
    const char* kgp = (const char*)(kb + base) + ghb + (((t0 >> 3) << 7) + cbs);
    const char* vgp = (const char*)(vtb + ((size_t)bh << 18)) + ghb + (((t0 >> 3) << 7) + cbs);
    char* const gb = smem + wg * 40960;
    char* K0p = gb +     0 + wv * 2048;  const short* Kr0 = (const short*)(gb);
    char* K1p = gb +  8192 + wv * 2048;  const short* Kr1 = (const short*)(gb + 8192);
    char* V0p = gb + 16384 + wv * 2048;  const short* Vr0 = (const short*)(gb + 16384);
    char* V1p = gb + 24576 + wv * 2048;  const short* Vr1 = (const short*)(gb + 24576);
    char* V2p = gb + 32768 + wv * 2048;  const short* Vr2 = (const short*)(gb + 32768);

    bf16x8 paA[4], paB[4];   // P fragments per kv-16-block (A-operand for PV)

    #define STAGE(klp, vlp, TI) do {                                       \
        _Pragma("unroll")                                                  \
        for (int i_ = 0; i_ < 2; ++i_) {                                   \
            gl16(kgp + (TI) * 8192 + i_ * 1024, (klp) + i_ * 1024);        \
            gl16(vgp + (TI) * 8192 + i_ * 1024, (vlp) + i_ * 1024);        \
        } } while (0)

    #define MFMA32(a_, b_, c_) __builtin_amdgcn_mfma_f32_32x32x16_bf16(a_, b_, c_, 0, 0, 0)

    // One 32-kv block: QK (4 MFMA) -> PV(prev) same d-block (4 MFMA) -> exp2/pack
    #define QKPV(KRD, VPR, B2, ACC, PAP, PAN) do {                              \
        f32x16 s_;                                                              \
        _Pragma("unroll")                                                       \
        for (int z_ = 0; z_ < 16; ++z_) s_[z_] = 0.f;                           \
        {                                                                       \
            bf16x8 k0_ = *(const bf16x8*)(&(KRD)[swz((B2) * 32 + l31,  0 + h8)]); \
            bf16x8 k1_ = *(const bf16x8*)(&(KRD)[swz((B2) * 32 + l31, 16 + h8)]); \
            bf16x8 k2_ = *(const bf16x8*)(&(KRD)[swz((B2) * 32 + l31, 32 + h8)]); \
            bf16x8 k3_ = *(const bf16x8*)(&(KRD)[swz((B2) * 32 + l31, 48 + h8)]); \
            s_ = MFMA32(k0_, qf0, s_);                                          \
            s_ = MFMA32(k1_, qf1, s_);                                          \
            s_ = MFMA32(k2_, qf2, s_);                                          \
            s_ = MFMA32(k3_, qf3, s_);                                          \
        }                                                                       \
        {                                                                       \
            bf16x8 v0_ = *(const bf16x8*)(&(VPR)[swz((B2) * 32 + l31,  0 + h8)]); \
            bf16x8 v1_ = *(const bf16x8*)(&(VPR)[swz((B2) * 32 + l31, 16 + h8)]); \
            bf16x8 v2_ = *(const bf16x8*)(&(VPR)[swz((B2) * 32 + l31, 32 + h8)]); \
            bf16x8 v3_ = *(const bf16x8*)(&(VPR)[swz((B2) * 32 + l31, 48 + h8)]); \
            ACC = MFMA32((PAP)[0], v0_, ACC);                                   \
            ACC = MFMA32((PAP)[1], v1_, ACC);                                   \
            ACC = MFMA32((PAP)[2], v2_, ACC);                                   \
            ACC = MFMA32((PAP)[3], v3_, ACC);                                   \
        }                                                                       \
        _Pragma("unroll")                                                       \
        for (int e_ = 0; e_ < 8; ++e_) {                                        \
            float p0_ = __builtin_amdgcn_exp2f(s_[e_]);                         \
            float p1_ = __builtin_amdgcn_exp2f(s_[8 + e_]);                     \
            lsum += p0_ + p1_;                                                  \
            (PAN)[(B2) * 2][e_]     = f2bf(p0_);                                \
            (PAN)[(B2) * 2 + 1][e_] = f2bf(p1_);                                \
        }                                                                       \
    } while (0)

    #define BODY(TILE, KRD, VPR, KSTP, VSTP, PAP, PAN, DOSTG) do {         \
        asm volatile("s_waitcnt vmcnt(0)" ::: "memory");                   \
        __syncthreads();                                                   \
        if (DOSTG) { STAGE(KSTP, VSTP, (TILE) + 1); }                      \
        QKPV(KRD, VPR, 0, accA, PAP, PAN);                                 \
        QKPV(KRD, VPR, 1, accB, PAP, PAN);                                 \
    } while (0)

    // prologue: tile 0 (QK + exp2 only, into paA)
    STAGE(K0p, V0p, 0);
    asm volatile("s_waitcnt vmcnt(0)" ::: "memory");
    __syncthreads();
    STAGE(K1p, V1p, 1);
    #pragma unroll
    for (int B2 = 0; B2 < 2; ++B2) {
        f32x16 s;
        #pragma unroll
        for (int z = 0; z < 16; ++z) s[z] = 0.f;
        bf16x8 k0 = *(const bf16x8*)(&Kr0[swz(B2 * 32 + l31,  0 + h8)]);
        bf16x8 k1 = *(const bf16x8*)(&Kr0[swz(B2 * 32 + l31, 16 + h8)]);
        bf16x8 k2 = *(const bf16x8*)(&Kr0[swz(B2 * 32 + l31, 32 + h8)]);
        bf16x8 k3 = *(const bf16x8*)(&Kr0[swz(B2 * 32 + l31, 48 + h8)]);
        s = MFMA32(k0, qf0, s);
        s = MFMA32(k1, qf1, s);
        s = MFMA32(k2, qf2, s);
        s = MFMA32(k3, qf3, s);
        #pragma unroll
        for (int e = 0; e < 8; ++e) {
            float p0 = __builtin_amdgcn_exp2f(s[e]);
            float p1 = __builtin_amdgcn_exp2f(s[8 + e]);
            lsum += p0 + p1;
            paA[B2 * 2][e]     = f2bf(p0);
            paA[B2 * 2 + 1][e] = f2bf(p1);
        }
    }

    // main: tiles 1..30 in 6-unrolled groups (periodic buffer pattern), then 31
    for (int i = 0; i < 5; ++i) {
        BODY(6 * i + 1, Kr1, Vr0, K0p, V2p, paA, paB, 1);
        BODY(6 * i + 2, Kr0, Vr1, K1p, V0p, paB, paA, 1);
        BODY(6 * i + 3, Kr1, Vr2, K0p, V1p, paA, paB, 1);
        BODY(6 * i + 4, Kr0, Vr0, K1p, V2p, paB, paA, 1);
        BODY(6 * i + 5, Kr1, Vr1, K0p, V0p, paA, paB, 1);
        BODY(6 * i + 6, Kr0, Vr2, K1p, V1p, paB, paA, 1);
    }
    BODY(31, Kr1, Vr0, K0p, V2p, paA, paB, 0);

    // epilogue PV for tile 31 (pa = paB, V = Vr1)
    {
        bf16x8 v0 = *(const bf16x8*)(&Vr1[swz(l31,  0 + h8)]);
        bf16x8 v1 = *(const bf16x8*)(&Vr1[swz(l31, 16 + h8)]);
        bf16x8 v2 = *(const bf16x8*)(&Vr1[swz(l31, 32 + h8)]);
        bf16x8 v3 = *(const bf16x8*)(&Vr1[swz(l31, 48 + h8)]);
        accA = MFMA32(paB[0], v0, accA);
        accA = MFMA32(paB[1], v1, accA);
        accA = MFMA32(paB[2], v2, accA);
        accA = MFMA32(paB[3], v3, accA);
        bf16x8 w0 = *(const bf16x8*)(&Vr1[swz(32 + l31,  0 + h8)]);
        bf16x8 w1 = *(const bf16x8*)(&Vr1[swz(32 + l31, 16 + h8)]);
        bf16x8 w2 = *(const bf16x8*)(&Vr1[swz(32 + l31, 32 + h8)]);
        bf16x8 w3 = *(const bf16x8*)(&Vr1[swz(32 + l31, 48 + h8)]);
        accB = MFMA32(paB[0], w0, accB);
        accB = MFMA32(paB[1], w1, accB);
        accB = MFMA32(paB[2], w2, accB);
        accB = MFMA32(paB[3], w3, accB);
    }
    #undef BODY
    #undef QKPV
    #undef MFMA32
    #undef STAGE

    // ---- combine the two kv-halves: O = (O0+O1), l = (l0+l1); then normalize ----
    __syncthreads();   // all K/V reads done; smem reusable as f32 exchange buffer
    float* xch = (float*)smem;
    const int xi = (wv * 64 + lane) * 36;   // 33 floats used, stride 36
    if (wg == 1) {
        #pragma unroll
        for (int di = 0; di < 4; ++di) {
            f32x4 ta = { accA[di * 4], accA[di * 4 + 1], accA[di * 4 + 2], accA[di * 4 + 3] };
            f32x4 tb = { accB[di * 4], accB[di * 4 + 1], accB[di * 4 + 2], accB[di * 4 + 3] };
            *(f32x4*)(xch + xi + di * 4)      = ta;
            *(f32x4*)(xch + xi + 16 + di * 4) = tb;
        }
        xch[xi + 32] = lsum;
    }
    __syncthreads();
    if (wg == 0) {
        #pragma unroll
        for (int di = 0; di < 4; ++di) {
            f32x4 ta = *(const f32x4*)(xch + xi + di * 4);
            f32x4 tb = *(const f32x4*)(xch + xi + 16 + di * 4);
            #pragma unroll
            for (int r = 0; r < 4; ++r) {
                accA[di * 4 + r] += ta[r];
                accB[di * 4 + r] += tb[r];
            }
        }
        lsum += xch[xi + 32];
        const float ltot = lsum + __shfl_xor(lsum, 32, 64);
        const float linv = 1.0f / ltot;   // lane L holds 1/l for q = L&31
        #pragma unroll
        for (int r = 0; r < 16; ++r) {
            const int qrow = (r & 3) + 8 * (r >> 2) + ((lane >> 5) << 2);
            const float il = __shfl(linv, qrow, 64);
            const int qn = q0 + wv * 32 + qrow;
            const size_t off = ((size_t)(b * SEQ + qn) << 9) + h * 64 + l31;
            ob[off]      = f2bf(accA[r] * il);
            ob[off + 32] = f2bf(accB[r] * il);
        }
    }
}

// ---------------- proj GEMM (bf16 via gload_lds) + bias + residual: y = x + ao@w^T + bp
__global__ __launch_bounds__(256) void proj_k(
    const short* __restrict__ ao, const short* __restrict__ wpb,
    const float* __restrict__ bp, const float* __restrict__ x,
    float* __restrict__ y)
{
    __shared__ alignas(16) short As[2][128 * 64];
    __shared__ alignas(16) short Bs[2][128 * 64];
    const int tid  = threadIdx.x;
    const int lane = tid & 63;
    const int l15  = lane & 15;
    const int lg   = lane >> 4;
    const int wv   = tid >> 6;
    const int wy   = wv >> 1, wx = wv & 1;
    const int m0 = blockIdx.x * 128;
    const int n0 = blockIdx.y * 128;

    const f32x4 fzero = {0.f, 0.f, 0.f, 0.f};
    f32x4 acc[4][4];
    #pragma unroll
    for (int i = 0; i < 4; ++i)
        #pragma unroll
        for (int j = 0; j < 4; ++j)
            acc[i][j] = fzero;

    const int row0 = wv * 8 + (lane >> 3);
    const int cb   = ((lane & 7) ^ (lane >> 3)) << 4;
    const char* agp = (const char*)ao  + (size_t)(m0 + row0) * 1024 + cb;
    const char* bgp = (const char*)wpb + (size_t)(n0 + row0) * 1024 + cb;
    char* al0 = (char*)&As[0][0] + wv * 1024;
    char* al1 = (char*)&As[1][0] + wv * 1024;
    char* bl0 = (char*)&Bs[0][0] + wv * 1024;
    char* bl1 = (char*)&Bs[1][0] + wv * 1024;

    #define PSTAGE(al, bl, kofs) do {                                  \
        _Pragma("unroll")                                              \
        for (int i_ = 0; i_ < 4; ++i_) {                               \
            gl16(agp + (kofs) + i_ * 32768, (al) + i_ * 4096);         \
            gl16(bgp + (kofs) + i_ * 32768, (bl) + i_ * 4096);         \
        } } while (0)

    PSTAGE(al0, bl0, 0);

    int cur = 0;
    for (int k0 = 0; k0 < CDIM; k0 += 64) {
        asm volatile("s_waitcnt vmcnt(0)" ::: "memory");
        __syncthreads();
        if (k0 + 64 < CDIM) {
            if (cur == 0) PSTAGE(al1, bl1, (k0 + 64) * 2);
            else          PSTAGE(al0, bl0, (k0 + 64) * 2);
        }
        const short* Ac = cur ? &As[1][0] : &As[0][0];
        const short* Bc = cur ? &Bs[1][0] : &Bs[0][0];

        #pragma unroll
        for (int ks = 0; ks < 2; ++ks) {
            bf16x8 afr[4], bfr[4];
            #pragma unroll
            for (int i = 0; i < 4; ++i) {
                afr[i] = *(const bf16x8*)(&Ac[swz(wy * 64 + i * 16 + l15, ks * 32 + lg * 8)]);
                bfr[i] = *(const bf16x8*)(&Bc[swz(wx * 64 + i * 16 + l15, ks * 32 + lg * 8)]);
            }
            #pragma unroll
            for (int i = 0; i < 4; ++i)
                #pragma unroll
                for (int j = 0; j < 4; ++j)
                    acc[i][j] = __builtin_amdgcn_mfma_f32_16x16x32_bf16(afr[i], bfr[j], acc[i][j], 0, 0, 0);
        }
        cur ^= 1;
    }
    #undef PSTAGE

    #pragma unroll
    for (int i = 0; i < 4; ++i) {
        #pragma unroll
        for (int j = 0; j < 4; ++j) {
            const int d = n0 + wx * 64 + j * 16 + l15;
            #pragma unroll
            for (int r = 0; r < 4; ++r) {
                const int m = m0 + wy * 64 + i * 16 + lg * 4 + r;
                const size_t idx = (size_t)m * CDIM + d;
                y[idx] = acc[i][j][r] + bp[d] + x[idx];
            }
        }
    }
}

// ---------------- LayerNorm in place over d_out rows (512 f32 each), 1 wave/row
__global__ __launch_bounds__(256) void ln_k(
    float* __restrict__ y, const float* __restrict__ gm, const float* __restrict__ bt)
{
    const int lane = threadIdx.x & 63;
    const int row  = blockIdx.x * 4 + (threadIdx.x >> 6);
    float* p = y + (size_t)row * CDIM;
    float4 a = *(const float4*)(p + lane * 4);
    float4 b = *(const float4*)(p + 256 + lane * 4);
    float s = a.x + a.y + a.z + a.w + b.x + b.y + b.z + b.w;
    float q = a.x * a.x + a.y * a.y + a.z * a.z + a.w * a.w
            + b.x * b.x + b.y * b.y + b.z * b.z + b.w * b.w;
    #pragma unroll
    for (int mm = 1; mm < 64; mm <<= 1) {
        s += __shfl_xor(s, mm, 64);
        q += __shfl_xor(q, mm, 64);
    }
    const float mean = s * (1.0f / CDIM);
    const float var  = q * (1.0f / CDIM) - mean * mean;
    const float inv  = rsqrtf(var + 1e-5f);
    float4 g0 = *(const float4*)(gm + lane * 4);
    float4 g1 = *(const float4*)(gm + 256 + lane * 4);
    float4 t0 = *(const float4*)(bt + lane * 4);
    float4 t1 = *(const float4*)(bt + 256 + lane * 4);
    float4 r0, r1;
    r0.x = (a.x - mean) * inv * g0.x + t0.x;
    r0.y = (a.y - mean) * inv * g0.y + t0.y;
    r0.z = (a.z - mean) * inv * g0.z + t0.z;
    r0.w = (a.w - mean) * inv * g0.w + t0.w;
    r1.x = (b.x - mean) * inv * g1.x + t1.x;
    r1.y = (b.y - mean) * inv * g1.y + t1.y;
    r1.z = (b.z - mean) * inv * g1.z + t1.z;
    r1.w = (b.w - mean) * inv * g1.w + t1.w;
    *(float4*)(p + lane * 4) = r0;
    *(float4*)(p + 256 + lane * 4) = r1;
}

extern "C" void kernel_launch(void* const* d_in, const int* in_sizes, int n_in,
                              void* d_out, int out_size, void* d_ws, size_t ws_size,
                              hipStream_t stream)
{
    const float* x      = (const float*)d_in[0];
    const float* w_qkv  = (const float*)d_in[1];
    const float* w_proj = (const float*)d_in[2];
    const float* b_proj = (const float*)d_in[3];
    const float* gamma  = (const float*)d_in[4];
    const float* beta   = (const float*)d_in[5];
    float* out = (float*)d_out;

    const size_t qkv_elems = (size_t)16 * SEQ * HDIM;
    short* qb    = (short*)d_ws;
    short* kb    = qb + qkv_elems;
    short* vtb   = kb + qkv_elems;
    short* ob    = vtb + qkv_elems;
    short* xb    = ob;                     // alias: xb dead before attn writes ob
    short* wqkvb = ob + qkv_elems;
    short* wpb   = wqkvb + (size_t)3 * CDIM * CDIM;

    cvt3_k    <<<dim3(1024),   256, 0, stream>>>(
        x, xb, (2 * SEQ * CDIM) / 4,
        w_qkv, wqkvb, (3 * CDIM * CDIM) / 4,
        w_proj, wpb, (CDIM * CDIM) / 4);
    qkv_gemm_k<<<dim3(64, 12), 256, 0, stream>>>(xb, wqkvb, qb, kb, vtb);
    attn_k    <<<dim3(512),    512, 0, stream>>>(qb, kb, vtb, ob);
    proj_k    <<<dim3(64, 4),  256, 0, stream>>>(ob, wpb, b_proj, x, out);
    ln_k      <<<dim3(2048),   256, 0, stream>>>(out, gamma, beta);
}

// Round 14
// 112.378 us; speedup vs baseline: 1.0818x; 1.0818x over previous
//
#include <hip/hip_runtime.h>
#include <hip/hip_bf16.h>

#define SEQ    4096
#define CDIM   512
#define NHEADS 8
#define HDIM   64
// fold softmax scale and log2(e) into Q once: exp(s*SCALE) == exp2(s')
#define QSCALE 0.18033688f   // 0.125 * 1.4426950408889634

typedef __attribute__((ext_vector_type(4))) float f32x4;
typedef __attribute__((ext_vector_type(8))) short bf16x8;

// LDS swizzle for tiles with 64-bf16 (128B) row stride: spread rows across banks.
__device__ __forceinline__ int swz(int row, int col) {
    int b = (row << 7) + (col << 1);
    b ^= (row & 7) << 4;
    return b >> 1;
}

__device__ __forceinline__ short f2bf(float f) {
    union { __hip_bfloat16 h; short s; } u;
    u.h = __float2bfloat16(f);
    return u.s;
}

// async global->LDS, 16B per lane; LDS dest = wave-uniform base + lane*16
__device__ __forceinline__ void gl16(const void* g, void* l) {
    __builtin_amdgcn_global_load_lds(
        (const __attribute__((address_space(1))) unsigned int*)g,
        (__attribute__((address_space(3))) unsigned int*)l,
        16, 0, 0);
}

// ---------------- f32 -> bf16 pre-pass for all three arrays (one launch)
__global__ __launch_bounds__(256) void cvt3_k(
    const float* __restrict__ a0, short* __restrict__ o0, int c0,
    const float* __restrict__ a1, short* __restrict__ o1, int c1,
    const float* __restrict__ a2, short* __restrict__ o2, int c2)
{
    const int total = c0 + c1 + c2;
    int i = blockIdx.x * 256 + threadIdx.x;
    const int stride = gridDim.x * 256;
    for (; i < total; i += stride) {
        const float* a; short* o; int j;
        if (i < c0)           { a = a0; o = o0; j = i; }
        else if (i < c0 + c1) { a = a1; o = o1; j = i - c0; }
        else                  { a = a2; o = o2; j = i - c0 - c1; }
        float4 v = ((const float4*)a)[j];
        short4 r;
        r.x = f2bf(v.x); r.y = f2bf(v.y); r.z = f2bf(v.z); r.w = f2bf(v.w);
        ((short4*)o)[j] = r;
    }
}

// ---------------- QKV GEMM (bf16 inputs): xb[8192,512] @ wb[1536,512]^T
__global__ __launch_bounds__(256) void qkv_gemm_k(
    const short* __restrict__ xb, const short* __restrict__ wb,
    short* __restrict__ qb, short* __restrict__ kb, short* __restrict__ vtb)
{
    __shared__ alignas(16) short As[2][128 * 64];
    __shared__ alignas(16) short Bs[2][128 * 64];
    const int tid  = threadIdx.x;
    const int lane = tid & 63;
    const int l15  = lane & 15;
    const int lg   = lane >> 4;
    const int wv   = tid >> 6;
    const int wy   = wv >> 1, wx = wv & 1;
    const int m0 = blockIdx.x * 128;
    const int n0 = blockIdx.y * 128;

    const f32x4 fzero = {0.f, 0.f, 0.f, 0.f};
    f32x4 acc[4][4];
    #pragma unroll
    for (int i = 0; i < 4; ++i)
        #pragma unroll
        for (int j = 0; j < 4; ++j)
            acc[i][j] = fzero;

    const int row0 = wv * 8 + (lane >> 3);
    const int cb   = ((lane & 7) ^ (lane >> 3)) << 4;
    const char* agp = (const char*)xb + (size_t)(m0 + row0) * 1024 + cb;
    const char* bgp = (const char*)wb + (size_t)(n0 + row0) * 1024 + cb;
    char* al0 = (char*)&As[0][0] + wv * 1024;
    char* al1 = (char*)&As[1][0] + wv * 1024;
    char* bl0 = (char*)&Bs[0][0] + wv * 1024;
    char* bl1 = (char*)&Bs[1][0] + wv * 1024;

    #define QSTAGE(al, bl, kofs) do {                                  \
        _Pragma("unroll")                                              \
        for (int i_ = 0; i_ < 4; ++i_) {                               \
            gl16(agp + (kofs) + i_ * 32768, (al) + i_ * 4096);         \
            gl16(bgp + (kofs) + i_ * 32768, (bl) + i_ * 4096);         \
        } } while (0)

    QSTAGE(al0, bl0, 0);

    int cur = 0;
    for (int k0 = 0; k0 < CDIM; k0 += 64) {
        asm volatile("s_waitcnt vmcnt(0)" ::: "memory");
        __syncthreads();
        if (k0 + 64 < CDIM) {
            if (cur == 0) QSTAGE(al1, bl1, (k0 + 64) * 2);
            else          QSTAGE(al0, bl0, (k0 + 64) * 2);
        }
        const short* Ac = cur ? &As[1][0] : &As[0][0];
        const short* Bc = cur ? &Bs[1][0] : &Bs[0][0];

        #pragma unroll
        for (int ks = 0; ks < 2; ++ks) {
            bf16x8 afr[4], bfr[4];
            #pragma unroll
            for (int i = 0; i < 4; ++i) {
                afr[i] = *(const bf16x8*)(&Ac[swz(wy * 64 + i * 16 + l15, ks * 32 + lg * 8)]);
                bfr[i] = *(const bf16x8*)(&Bc[swz(wx * 64 + i * 16 + l15, ks * 32 + lg * 8)]);
            }
            #pragma unroll
            for (int i = 0; i < 4; ++i)
                #pragma unroll
                for (int j = 0; j < 4; ++j)
                    acc[i][j] = __builtin_amdgcn_mfma_f32_16x16x32_bf16(afr[i], bfr[j], acc[i][j], 0, 0, 0);
        }
        cur ^= 1;
    }
    #undef QSTAGE

    // epilogue: Q (scaled), K as [bh][n][64]; V^T blocked per 32 kv with col-perm
    #pragma unroll
    for (int j = 0; j < 4; ++j) {
        const int d = n0 + wx * 64 + j * 16 + l15;
        const int s = d >> 9;
        const int h = (d >> 6) & 7;
        const int e = d & 63;
        #pragma unroll
        for (int i = 0; i < 4; ++i) {
            #pragma unroll
            for (int r = 0; r < 4; ++r) {
                const int m  = m0 + wy * 64 + i * 16 + lg * 4 + r;
                const int bb = m >> 12;
                const int n  = m & (SEQ - 1);
                const int bh = bb * NHEADS + h;
                const float v = acc[i][j][r];
                if (s == 0) {
                    qb[(((size_t)bh * SEQ + n) << 6) + e] = f2bf(v * QSCALE);
                } else if (s == 1) {
                    kb[(((size_t)bh * SEQ + n) << 6) + e] = f2bf(v);
                } else {
                    // V blocked [bh][n>>5][d=e][cp]: within-32 kv perm
                    // cp(kv) = (kv&3) | ((kv&0x0C)<<1) | ((kv&0x10)>>2)
                    const int c  = n & 31;
                    const int cp = (c & 3) | ((c & 0x0C) << 1) | ((c & 0x10) >> 2);
                    vtb[((size_t)bh << 18) + ((size_t)(n >> 5) << 11) + (e << 5) + cp] = f2bf(v);
                }
            }
        }
    }
}

// ---------------- Flash attention v10: counted-vmcnt pipeline (T3+T4).
//   Split-KV (2 groups x 4 waves), 32-kv tiles, K[4]/V[4] group-shared buffers,
//   per tile: s_waitcnt vmcnt(4) -> raw s_barrier -> stage(t+3) -> compute(t).
//   Loads for tiles t+1,t+2 stay in flight across the barrier (never drain to 0).
__global__ __launch_bounds__(512) void attn_k(
    const short* __restrict__ qb, const short* __restrict__ kb, const short* __restrict__ vtb,
    short* __restrict__ ob)
{
    __shared__ alignas(16) char smem[65536];   // 2 groups x (K[4]+V[4]) x 4KB
    const int tid  = threadIdx.x;
    const int lane = tid & 63;
    const int l15  = lane & 15;
    const int lg   = lane >> 4;
    const int wv   = (tid >> 6) & 3;    // wave within group
    const int wg   = tid >> 8;          // wave group = kv half
    const int lin  = blockIdx.x;
    const int bh   = lin & 15;          // same-bh blocks land on one XCD (L2 locality)
    const int q0   = (lin >> 4) << 7;   // 128 q-rows per block
    const int b    = bh >> 3, h = bh & 7;
    const size_t base = (size_t)bh * SEQ * HDIM;

    // Q fragments: wave owns 32 q-rows (2 fragments of 16)
    bf16x8 qf[2][2];
    #pragma unroll
    for (int qi = 0; qi < 2; ++qi) {
        const short* qp = qb + base + (size_t)(q0 + wv * 32 + qi * 16 + l15) * HDIM + lg * 8;
        qf[qi][0] = *(const bf16x8*)(qp);
        qf[qi][1] = *(const bf16x8*)(qp + 32);
    }

    const f32x4 fzero = {0.f, 0.f, 0.f, 0.f};
    f32x4 acc[2][4];    // partial O for this kv half
    f32x4 lacc[2];      // partial row sums via ones-MFMA
    #pragma unroll
    for (int qi = 0; qi < 2; ++qi) {
        lacc[qi] = fzero;
        #pragma unroll
        for (int di = 0; di < 4; ++di) acc[qi][di] = fzero;
    }

    bf16x8 ones;
    #pragma unroll
    for (int e = 0; e < 8; ++e) ones[e] = (short)0x3F80;  // bf16 1.0

    // staging: slot t0 = wv*64 + lane in [0,256) covers a 4KB tile (32 rows x 128B);
    // row = t0>>3, chunk ((t0&7)^((t0>>3)&7))<<4 (verified involution).
    // K tile = 32 kv x 64 d; V tile = one 32-kv block [64 d][32 kv'] = same 4KB shape.
    const int t0  = wv * 64 + lane;
    const int cbs = ((t0 & 7) ^ ((t0 >> 3) & 7)) << 4;
    const int ghb = wg * 262144;   // kv-half byte offset (2048 kv * 128B)
    const char* kgp = (const char*)(kb + base) + ghb + (((t0 >> 3) << 7) + cbs);
    const char* vgp = (const char*)(vtb + ((size_t)bh << 18)) + ghb + (((t0 >> 3) << 7) + cbs);
    char* const gb = smem + wg * 32768;
    // read bases (group-wide) and stage dests (per-wave) for the 4 buffers
    const short* Kb0 = (const short*)(gb);
    const short* Kb1 = (const short*)(gb + 4096);
    const short* Kb2 = (const short*)(gb + 8192);
    const short* Kb3 = (const short*)(gb + 12288);
    const short* Vb0 = (const short*)(gb + 16384);
    const short* Vb1 = (const short*)(gb + 20480);
    const short* Vb2 = (const short*)(gb + 24576);
    const short* Vb3 = (const short*)(gb + 28672);
    char* Ks0 = gb +     0 + wv * 1024;
    char* Ks1 = gb +  4096 + wv * 1024;
    char* Ks2 = gb +  8192 + wv * 1024;
    char* Ks3 = gb + 12288 + wv * 1024;
    char* Vs0 = gb + 16384 + wv * 1024;
    char* Vs1 = gb + 20480 + wv * 1024;
    char* Vs2 = gb + 24576 + wv * 1024;
    char* Vs3 = gb + 28672 + wv * 1024;

    #define MFMA16(a_, b_, c_) __builtin_amdgcn_mfma_f32_16x16x32_bf16(a_, b_, c_, 0, 0, 0)

    #define STAGE2(T_, KS, VS) do {                    \
        gl16(kgp + (T_) * 4096, (KS));                 \
        gl16(vgp + (T_) * 4096, (VS));                 \
    } while (0)

    // compute one 32-kv tile: QK (8 MFMA) -> exp2/pack -> lacc (2) -> PV (8)
    #define COMPUTE(KR, VR) do {                                               \
        f32x4 s00 = fzero, s01 = fzero, s10 = fzero, s11 = fzero;              \
        {                                                                      \
            bf16x8 kf_;                                                        \
            kf_ = *(const bf16x8*)(&(KR)[swz(l15, lg * 8)]);                   \
            s00 = MFMA16(kf_, qf[0][0], s00);                                  \
            s10 = MFMA16(kf_, qf[1][0], s10);                                  \
            kf_ = *(const bf16x8*)(&(KR)[swz(l15, 32 + lg * 8)]);              \
            s00 = MFMA16(kf_, qf[0][1], s00);                                  \
            s10 = MFMA16(kf_, qf[1][1], s10);                                  \
            kf_ = *(const bf16x8*)(&(KR)[swz(16 + l15, lg * 8)]);              \
            s01 = MFMA16(kf_, qf[0][0], s01);                                  \
            s11 = MFMA16(kf_, qf[1][0], s11);                                  \
            kf_ = *(const bf16x8*)(&(KR)[swz(16 + l15, 32 + lg * 8)]);         \
            s01 = MFMA16(kf_, qf[0][1], s01);                                  \
            s11 = MFMA16(kf_, qf[1][1], s11);                                  \
        }                                                                      \
        bf16x8 pa0, pa1;                                                       \
        _Pragma("unroll")                                                      \
        for (int r_ = 0; r_ < 4; ++r_) {                                       \
            pa0[r_]     = f2bf(__builtin_amdgcn_exp2f(s00[r_]));               \
            pa0[4 + r_] = f2bf(__builtin_amdgcn_exp2f(s01[r_]));               \
            pa1[r_]     = f2bf(__builtin_amdgcn_exp2f(s10[r_]));               \
            pa1[4 + r_] = f2bf(__builtin_amdgcn_exp2f(s11[r_]));               \
        }                                                                      \
        lacc[0] = MFMA16(pa0, ones, lacc[0]);                                  \
        lacc[1] = MFMA16(pa1, ones, lacc[1]);                                  \
        _Pragma("unroll")                                                      \
        for (int di_ = 0; di_ < 4; ++di_) {                                    \
            bf16x8 vf_ = *(const bf16x8*)(&(VR)[swz(di_ * 8 + (l15 >> 1),      \
                                                    (l15 & 1) * 32 + lg * 8)]);\
            acc[0][di_] = MFMA16(pa0, vf_, acc[0][di_]);                       \
            acc[1][di_] = MFMA16(pa1, vf_, acc[1][di_]);                       \
        }                                                                      \
    } while (0)

    #define STEP(T_, KR, VR, KS, VS) do {                          \
        asm volatile("s_waitcnt vmcnt(4)" ::: "memory");           \
        __builtin_amdgcn_s_barrier();                              \
        asm volatile("" ::: "memory");                             \
        if ((T_) < 61) { STAGE2((T_) + 3, KS, VS); }               \
        COMPUTE(KR, VR);                                           \
    } while (0)

    // prologue: stage tiles 0,1,2 (6 loads in flight)
    STAGE2(0, Ks0, Vs0);
    STAGE2(1, Ks1, Vs1);
    STAGE2(2, Ks2, Vs2);

    for (int it = 0; it < 16; ++it) {
        const int t = it << 2;
        STEP(t + 0, Kb0, Vb0, Ks3, Vs3);
        STEP(t + 1, Kb1, Vb1, Ks0, Vs0);
        STEP(t + 2, Kb2, Vb2, Ks1, Vs1);
        STEP(t + 3, Kb3, Vb3, Ks2, Vs2);
    }
    #undef STEP
    #undef COMPUTE
    #undef STAGE2
    #undef MFMA16

    // ---- combine the two kv-halves: O = (O0+O1)/(l0+l1) ----
    __syncthreads();   // all K/V reads done; smem reusable as f32 exchange buffer
    float* xch = (float*)smem;
    const int xi = (wv * 64 + lane) * 44;   // 44 f32 stride: 16B-aligned, bank-spread
    if (wg == 1) {
        #pragma unroll
        for (int qi = 0; qi < 2; ++qi) {
            #pragma unroll
            for (int di = 0; di < 4; ++di)
                *(f32x4*)(xch + xi + qi * 16 + di * 4) = acc[qi][di];
            *(f32x4*)(xch + xi + 32 + qi * 4) = lacc[qi];
        }
    }
    __syncthreads();
    if (wg == 0) {
        #pragma unroll
        for (int qi = 0; qi < 2; ++qi) {
            #pragma unroll
            for (int di = 0; di < 4; ++di)
                acc[qi][di] += *(const f32x4*)(xch + xi + qi * 16 + di * 4);
            lacc[qi] += *(const f32x4*)(xch + xi + 32 + qi * 4);
        }
        #pragma unroll
        for (int qi = 0; qi < 2; ++qi) {
            float inv[4];
            #pragma unroll
            for (int r = 0; r < 4; ++r) inv[r] = 1.0f / lacc[qi][r];
            #pragma unroll
            for (int di = 0; di < 4; ++di) {
                const int e = di * 16 + l15;
                #pragma unroll
                for (int r = 0; r < 4; ++r) {
                    const int qn = q0 + wv * 32 + qi * 16 + lg * 4 + r;
                    ob[((size_t)(b * SEQ + qn) << 9) + h * 64 + e] = f2bf(acc[qi][di][r] * inv[r]);
                }
            }
        }
    }
}

// ---------------- proj GEMM (bf16 via gload_lds) + bias + residual: y = x + ao@w^T + bp
__global__ __launch_bounds__(256) void proj_k(
    const short* __restrict__ ao, const short* __restrict__ wpb,
    const float* __restrict__ bp, const float* __restrict__ x,
    float* __restrict__ y)
{
    __shared__ alignas(16) short As[2][128 * 64];
    __shared__ alignas(16) short Bs[2][128 * 64];
    const int tid  = threadIdx.x;
    const int lane = tid & 63;
    const int l15  = lane & 15;
    const int lg   = lane >> 4;
    const int wv   = tid >> 6;
    const int wy   = wv >> 1, wx = wv & 1;
    const int m0 = blockIdx.x * 128;
    const int n0 = blockIdx.y * 128;

    const f32x4 fzero = {0.f, 0.f, 0.f, 0.f};
    f32x4 acc[4][4];
    #pragma unroll
    for (int i = 0; i < 4; ++i)
        #pragma unroll
        for (int j = 0; j < 4; ++j)
            acc[i][j] = fzero;

    const int row0 = wv * 8 + (lane >> 3);
    const int cb   = ((lane & 7) ^ (lane >> 3)) << 4;
    const char* agp = (const char*)ao  + (size_t)(m0 + row0) * 1024 + cb;
    const char* bgp = (const char*)wpb + (size_t)(n0 + row0) * 1024 + cb;
    char* al0 = (char*)&As[0][0] + wv * 1024;
    char* al1 = (char*)&As[1][0] + wv * 1024;
    char* bl0 = (char*)&Bs[0][0] + wv * 1024;
    char* bl1 = (char*)&Bs[1][0] + wv * 1024;

    #define PSTAGE(al, bl, kofs) do {                                  \
        _Pragma("unroll")                                              \
        for (int i_ = 0; i_ < 4; ++i_) {                               \
            gl16(agp + (kofs) + i_ * 32768, (al) + i_ * 4096);         \
            gl16(bgp + (kofs) + i_ * 32768, (bl) + i_ * 4096);         \
        } } while (0)

    PSTAGE(al0, bl0, 0);

    int cur = 0;
    for (int k0 = 0; k0 < CDIM; k0 += 64) {
        asm volatile("s_waitcnt vmcnt(0)" ::: "memory");
        __syncthreads();
        if (k0 + 64 < CDIM) {
            if (cur == 0) PSTAGE(al1, bl1, (k0 + 64) * 2);
            else          PSTAGE(al0, bl0, (k0 + 64) * 2);
        }
        const short* Ac = cur ? &As[1][0] : &As[0][0];
        const short* Bc = cur ? &Bs[1][0] : &Bs[0][0];

        #pragma unroll
        for (int ks = 0; ks < 2; ++ks) {
            bf16x8 afr[4], bfr[4];
            #pragma unroll
            for (int i = 0; i < 4; ++i) {
                afr[i] = *(const bf16x8*)(&Ac[swz(wy * 64 + i * 16 + l15, ks * 32 + lg * 8)]);
                bfr[i] = *(const bf16x8*)(&Bc[swz(wx * 64 + i * 16 + l15, ks * 32 + lg * 8)]);
            }
            #pragma unroll
            for (int i = 0; i < 4; ++i)
                #pragma unroll
                for (int j = 0; j < 4; ++j)
                    acc[i][j] = __builtin_amdgcn_mfma_f32_16x16x32_bf16(afr[i], bfr[j], acc[i][j], 0, 0, 0);
        }
        cur ^= 1;
    }
    #undef PSTAGE

    #pragma unroll
    for (int i = 0; i < 4; ++i) {
        #pragma unroll
        for (int j = 0; j < 4; ++j) {
            const int d = n0 + wx * 64 + j * 16 + l15;
            #pragma unroll
            for (int r = 0; r < 4; ++r) {
                const int m = m0 + wy * 64 + i * 16 + lg * 4 + r;
                const size_t idx = (size_t)m * CDIM + d;
                y[idx] = acc[i][j][r] + bp[d] + x[idx];
            }
        }
    }
}

// ---------------- LayerNorm in place over d_out rows (512 f32 each), 1 wave/row
__global__ __launch_bounds__(256) void ln_k(
    float* __restrict__ y, const float* __restrict__ gm, const float* __restrict__ bt)
{
    const int lane = threadIdx.x & 63;
    const int row  = blockIdx.x * 4 + (threadIdx.x >> 6);
    float* p = y + (size_t)row * CDIM;
    float4 a = *(const float4*)(p + lane * 4);
    float4 b = *(const float4*)(p + 256 + lane * 4);
    float s = a.x + a.y + a.z + a.w + b.x + b.y + b.z + b.w;
    float q = a.x * a.x + a.y * a.y + a.z * a.z + a.w * a.w
            + b.x * b.x + b.y * b.y + b.z * b.z + b.w * b.w;
    #pragma unroll
    for (int mm = 1; mm < 64; mm <<= 1) {
        s += __shfl_xor(s, mm, 64);
        q += __shfl_xor(q, mm, 64);
    }
    const float mean = s * (1.0f / CDIM);
    const float var  = q * (1.0f / CDIM) - mean * mean;
    const float inv  = rsqrtf(var + 1e-5f);
    float4 g0 = *(const float4*)(gm + lane * 4);
    float4 g1 = *(const float4*)(gm + 256 + lane * 4);
    float4 t0 = *(const float4*)(bt + lane * 4);
    float4 t1 = *(const float4*)(bt + 256 + lane * 4);
    float4 r0, r1;
    r0.x = (a.x - mean) * inv * g0.x + t0.x;
    r0.y = (a.y - mean) * inv * g0.y + t0.y;
    r0.z = (a.z - mean) * inv * g0.z + t0.z;
    r0.w = (a.w - mean) * inv * g0.w + t0.w;
    r1.x = (b.x - mean) * inv * g1.x + t1.x;
    r1.y = (b.y - mean) * inv * g1.y + t1.y;
    r1.z = (b.z - mean) * inv * g1.z + t1.z;
    r1.w = (b.w - mean) * inv * g1.w + t1.w;
    *(float4*)(p + lane * 4) = r0;
    *(float4*)(p + 256 + lane * 4) = r1;
}

extern "C" void kernel_launch(void* const* d_in, const int* in_sizes, int n_in,
                              void* d_out, int out_size, void* d_ws, size_t ws_size,
                              hipStream_t stream)
{
    const float* x      = (const float*)d_in[0];
    const float* w_qkv  = (const float*)d_in[1];
    const float* w_proj = (const float*)d_in[2];
    const float* b_proj = (const float*)d_in[3];
    const float* gamma  = (const float*)d_in[4];
    const float* beta   = (const float*)d_in[5];
    float* out = (float*)d_out;

    const size_t qkv_elems = (size_t)16 * SEQ * HDIM;
    short* qb    = (short*)d_ws;
    short* kb    = qb + qkv_elems;
    short* vtb   = kb + qkv_elems;
    short* ob    = vtb + qkv_elems;
    short* xb    = ob;                     // alias: xb dead before attn writes ob
    short* wqkvb = ob + qkv_elems;
    short* wpb   = wqkvb + (size_t)3 * CDIM * CDIM;

    cvt3_k    <<<dim3(1024),   256, 0, stream>>>(
        x, xb, (2 * SEQ * CDIM) / 4,
        w_qkv, wqkvb, (3 * CDIM * CDIM) / 4,
        w_proj, wpb, (CDIM * CDIM) / 4);
    qkv_gemm_k<<<dim3(64, 12), 256, 0, stream>>>(xb, wqkvb, qb, kb, vtb);
    attn_k    <<<dim3(512),    512, 0, stream>>>(qb, kb, vtb, ob);
    proj_k    <<<dim3(64, 4),  256, 0, stream>>>(ob, wpb, b_proj, x, out);
    ln_k      <<<dim3(2048),   256, 0, stream>>>(out, gamma, beta);
}

// Round 15
// 111.259 us; speedup vs baseline: 1.0927x; 1.0101x over previous
//
#include <hip/hip_runtime.h>
#include <hip/hip_bf16.h>

#define SEQ    4096
#define CDIM   512
#define NHEADS 8
#define HDIM   64
// fold softmax scale and log2(e) into Q once: exp(s*SCALE) == exp2(s')
#define QSCALE 0.18033688f   // 0.125 * 1.4426950408889634

typedef __attribute__((ext_vector_type(4))) float f32x4;
typedef __attribute__((ext_vector_type(8))) short bf16x8;

// LDS swizzle for tiles with 64-bf16 (128B) row stride: spread rows across banks.
__device__ __forceinline__ int swz(int row, int col) {
    int b = (row << 7) + (col << 1);
    b ^= (row & 7) << 4;
    return b >> 1;
}

__device__ __forceinline__ short f2bf(float f) {
    union { __hip_bfloat16 h; short s; } u;
    u.h = __float2bfloat16(f);
    return u.s;
}

// async global->LDS, 16B per lane; LDS dest = wave-uniform base + lane*16
__device__ __forceinline__ void gl16(const void* g, void* l) {
    __builtin_amdgcn_global_load_lds(
        (const __attribute__((address_space(1))) unsigned int*)g,
        (__attribute__((address_space(3))) unsigned int*)l,
        16, 0, 0);
}

// ---------------- f32 -> bf16 pre-pass for all three arrays (one launch)
__global__ __launch_bounds__(256) void cvt3_k(
    const float* __restrict__ a0, short* __restrict__ o0, int c0,
    const float* __restrict__ a1, short* __restrict__ o1, int c1,
    const float* __restrict__ a2, short* __restrict__ o2, int c2)
{
    const int total = c0 + c1 + c2;
    int i = blockIdx.x * 256 + threadIdx.x;
    const int stride = gridDim.x * 256;
    for (; i < total; i += stride) {
        const float* a; short* o; int j;
        if (i < c0)           { a = a0; o = o0; j = i; }
        else if (i < c0 + c1) { a = a1; o = o1; j = i - c0; }
        else                  { a = a2; o = o2; j = i - c0 - c1; }
        float4 v = ((const float4*)a)[j];
        short4 r;
        r.x = f2bf(v.x); r.y = f2bf(v.y); r.z = f2bf(v.z); r.w = f2bf(v.w);
        ((short4*)o)[j] = r;
    }
}

// ---------------- QKV GEMM (bf16 inputs): xb[8192,512] @ wb[1536,512]^T
__global__ __launch_bounds__(256) void qkv_gemm_k(
    const short* __restrict__ xb, const short* __restrict__ wb,
    short* __restrict__ qb, short* __restrict__ kb, short* __restrict__ vtb)
{
    __shared__ alignas(16) short As[2][128 * 64];
    __shared__ alignas(16) short Bs[2][128 * 64];
    const int tid  = threadIdx.x;
    const int lane = tid & 63;
    const int l15  = lane & 15;
    const int lg   = lane >> 4;
    const int wv   = tid >> 6;
    const int wy   = wv >> 1, wx = wv & 1;
    const int m0 = blockIdx.x * 128;
    const int n0 = blockIdx.y * 128;

    const f32x4 fzero = {0.f, 0.f, 0.f, 0.f};
    f32x4 acc[4][4];
    #pragma unroll
    for (int i = 0; i < 4; ++i)
        #pragma unroll
        for (int j = 0; j < 4; ++j)
            acc[i][j] = fzero;

    const int row0 = wv * 8 + (lane >> 3);
    const int cb   = ((lane & 7) ^ (lane >> 3)) << 4;
    const char* agp = (const char*)xb + (size_t)(m0 + row0) * 1024 + cb;
    const char* bgp = (const char*)wb + (size_t)(n0 + row0) * 1024 + cb;
    char* al0 = (char*)&As[0][0] + wv * 1024;
    char* al1 = (char*)&As[1][0] + wv * 1024;
    char* bl0 = (char*)&Bs[0][0] + wv * 1024;
    char* bl1 = (char*)&Bs[1][0] + wv * 1024;

    #define QSTAGE(al, bl, kofs) do {                                  \
        _Pragma("unroll")                                              \
        for (int i_ = 0; i_ < 4; ++i_) {                               \
            gl16(agp + (kofs) + i_ * 32768, (al) + i_ * 4096);         \
            gl16(bgp + (kofs) + i_ * 32768, (bl) + i_ * 4096);         \
        } } while (0)

    QSTAGE(al0, bl0, 0);

    int cur = 0;
    for (int k0 = 0; k0 < CDIM; k0 += 64) {
        asm volatile("s_waitcnt vmcnt(0)" ::: "memory");
        __syncthreads();
        if (k0 + 64 < CDIM) {
            if (cur == 0) QSTAGE(al1, bl1, (k0 + 64) * 2);
            else          QSTAGE(al0, bl0, (k0 + 64) * 2);
        }
        const short* Ac = cur ? &As[1][0] : &As[0][0];
        const short* Bc = cur ? &Bs[1][0] : &Bs[0][0];

        #pragma unroll
        for (int ks = 0; ks < 2; ++ks) {
            bf16x8 afr[4], bfr[4];
            #pragma unroll
            for (int i = 0; i < 4; ++i) {
                afr[i] = *(const bf16x8*)(&Ac[swz(wy * 64 + i * 16 + l15, ks * 32 + lg * 8)]);
                bfr[i] = *(const bf16x8*)(&Bc[swz(wx * 64 + i * 16 + l15, ks * 32 + lg * 8)]);
            }
            #pragma unroll
            for (int i = 0; i < 4; ++i)
                #pragma unroll
                for (int j = 0; j < 4; ++j)
                    acc[i][j] = __builtin_amdgcn_mfma_f32_16x16x32_bf16(afr[i], bfr[j], acc[i][j], 0, 0, 0);
        }
        cur ^= 1;
    }
    #undef QSTAGE

    // epilogue: Q (scaled), K as [bh][n][64]; V^T blocked per 32 kv with col-perm
    #pragma unroll
    for (int j = 0; j < 4; ++j) {
        const int d = n0 + wx * 64 + j * 16 + l15;
        const int s = d >> 9;
        const int h = (d >> 6) & 7;
        const int e = d & 63;
        #pragma unroll
        for (int i = 0; i < 4; ++i) {
            #pragma unroll
            for (int r = 0; r < 4; ++r) {
                const int m  = m0 + wy * 64 + i * 16 + lg * 4 + r;
                const int bb = m >> 12;
                const int n  = m & (SEQ - 1);
                const int bh = bb * NHEADS + h;
                const float v = acc[i][j][r];
                if (s == 0) {
                    qb[(((size_t)bh * SEQ + n) << 6) + e] = f2bf(v * QSCALE);
                } else if (s == 1) {
                    kb[(((size_t)bh * SEQ + n) << 6) + e] = f2bf(v);
                } else {
                    // V blocked [bh][n>>5][d=e][cp]: within-32 kv perm
                    // cp(kv) = (kv&3) | ((kv&0x0C)<<1) | ((kv&0x10)>>2)
                    const int c  = n & 31;
                    const int cp = (c & 3) | ((c & 0x0C) << 1) | ((c & 0x10) >> 2);
                    vtb[((size_t)bh << 18) + ((size_t)(n >> 5) << 11) + (e << 5) + cp] = f2bf(v);
                }
            }
        }
    }
}

// ---------------- Flash attention v11: counted-vmcnt pipeline (T3+T4) + T5 setprio.
//   Split-KV (2 groups x 4 waves), 32-kv tiles, K[4]/V[4] group-shared buffers,
//   per tile: s_waitcnt vmcnt(4) -> raw s_barrier -> stage(t+3) -> compute(t).
//   setprio(1) around MFMA clusters (phase-split waves -> scheduler has roles).
__global__ __launch_bounds__(512) void attn_k(
    const short* __restrict__ qb, const short* __restrict__ kb, const short* __restrict__ vtb,
    short* __restrict__ ob)
{
    __shared__ alignas(16) char smem[65536];   // 2 groups x (K[4]+V[4]) x 4KB
    const int tid  = threadIdx.x;
    const int lane = tid & 63;
    const int l15  = lane & 15;
    const int lg   = lane >> 4;
    const int wv   = (tid >> 6) & 3;    // wave within group
    const int wg   = tid >> 8;          // wave group = kv half
    const int lin  = blockIdx.x;
    const int bh   = lin & 15;          // same-bh blocks land on one XCD (L2 locality)
    const int q0   = (lin >> 4) << 7;   // 128 q-rows per block
    const int b    = bh >> 3, h = bh & 7;
    const size_t base = (size_t)bh * SEQ * HDIM;

    // Q fragments: wave owns 32 q-rows (2 fragments of 16)
    bf16x8 qf[2][2];
    #pragma unroll
    for (int qi = 0; qi < 2; ++qi) {
        const short* qp = qb + base + (size_t)(q0 + wv * 32 + qi * 16 + l15) * HDIM + lg * 8;
        qf[qi][0] = *(const bf16x8*)(qp);
        qf[qi][1] = *(const bf16x8*)(qp + 32);
    }

    const f32x4 fzero = {0.f, 0.f, 0.f, 0.f};
    f32x4 acc[2][4];    // partial O for this kv half
    f32x4 lacc[2];      // partial row sums via ones-MFMA
    #pragma unroll
    for (int qi = 0; qi < 2; ++qi) {
        lacc[qi] = fzero;
        #pragma unroll
        for (int di = 0; di < 4; ++di) acc[qi][di] = fzero;
    }

    bf16x8 ones;
    #pragma unroll
    for (int e = 0; e < 8; ++e) ones[e] = (short)0x3F80;  // bf16 1.0

    // staging: slot t0 = wv*64 + lane in [0,256) covers a 4KB tile (32 rows x 128B);
    // row = t0>>3, chunk ((t0&7)^((t0>>3)&7))<<4 (verified involution).
    const int t0  = wv * 64 + lane;
    const int cbs = ((t0 & 7) ^ ((t0 >> 3) & 7)) << 4;
    const int ghb = wg * 262144;   // kv-half byte offset (2048 kv * 128B)
    const char* kgp = (const char*)(kb + base) + ghb + (((t0 >> 3) << 7) + cbs);
    const char* vgp = (const char*)(vtb + ((size_t)bh << 18)) + ghb + (((t0 >> 3) << 7) + cbs);
    char* const gb = smem + wg * 32768;
    const short* Kb0 = (const short*)(gb);
    const short* Kb1 = (const short*)(gb + 4096);
    const short* Kb2 = (const short*)(gb + 8192);
    const short* Kb3 = (const short*)(gb + 12288);
    const short* Vb0 = (const short*)(gb + 16384);
    const short* Vb1 = (const short*)(gb + 20480);
    const short* Vb2 = (const short*)(gb + 24576);
    const short* Vb3 = (const short*)(gb + 28672);
    char* Ks0 = gb +     0 + wv * 1024;
    char* Ks1 = gb +  4096 + wv * 1024;
    char* Ks2 = gb +  8192 + wv * 1024;
    char* Ks3 = gb + 12288 + wv * 1024;
    char* Vs0 = gb + 16384 + wv * 1024;
    char* Vs1 = gb + 20480 + wv * 1024;
    char* Vs2 = gb + 24576 + wv * 1024;
    char* Vs3 = gb + 28672 + wv * 1024;

    #define MFMA16(a_, b_, c_) __builtin_amdgcn_mfma_f32_16x16x32_bf16(a_, b_, c_, 0, 0, 0)

    #define STAGE2(T_, KS, VS) do {                    \
        gl16(kgp + (T_) * 4096, (KS));                 \
        gl16(vgp + (T_) * 4096, (VS));                 \
    } while (0)

    // compute one 32-kv tile: QK (8 MFMA) -> exp2/pack -> lacc (2) -> PV (8)
    #define COMPUTE(KR, VR) do {                                               \
        f32x4 s00 = fzero, s01 = fzero, s10 = fzero, s11 = fzero;              \
        __builtin_amdgcn_s_setprio(1);                                         \
        {                                                                      \
            bf16x8 kf_;                                                        \
            kf_ = *(const bf16x8*)(&(KR)[swz(l15, lg * 8)]);                   \
            s00 = MFMA16(kf_, qf[0][0], s00);                                  \
            s10 = MFMA16(kf_, qf[1][0], s10);                                  \
            kf_ = *(const bf16x8*)(&(KR)[swz(l15, 32 + lg * 8)]);              \
            s00 = MFMA16(kf_, qf[0][1], s00);                                  \
            s10 = MFMA16(kf_, qf[1][1], s10);                                  \
            kf_ = *(const bf16x8*)(&(KR)[swz(16 + l15, lg * 8)]);              \
            s01 = MFMA16(kf_, qf[0][0], s01);                                  \
            s11 = MFMA16(kf_, qf[1][0], s11);                                  \
            kf_ = *(const bf16x8*)(&(KR)[swz(16 + l15, 32 + lg * 8)]);         \
            s01 = MFMA16(kf_, qf[0][1], s01);                                  \
            s11 = MFMA16(kf_, qf[1][1], s11);                                  \
        }                                                                      \
        __builtin_amdgcn_s_setprio(0);                                         \
        bf16x8 pa0, pa1;                                                       \
        _Pragma("unroll")                                                      \
        for (int r_ = 0; r_ < 4; ++r_) {                                       \
            pa0[r_]     = f2bf(__builtin_amdgcn_exp2f(s00[r_]));               \
            pa0[4 + r_] = f2bf(__builtin_amdgcn_exp2f(s01[r_]));               \
            pa1[r_]     = f2bf(__builtin_amdgcn_exp2f(s10[r_]));               \
            pa1[4 + r_] = f2bf(__builtin_amdgcn_exp2f(s11[r_]));               \
        }                                                                      \
        __builtin_amdgcn_s_setprio(1);                                         \
        lacc[0] = MFMA16(pa0, ones, lacc[0]);                                  \
        lacc[1] = MFMA16(pa1, ones, lacc[1]);                                  \
        _Pragma("unroll")                                                      \
        for (int di_ = 0; di_ < 4; ++di_) {                                    \
            bf16x8 vf_ = *(const bf16x8*)(&(VR)[swz(di_ * 8 + (l15 >> 1),      \
                                                    (l15 & 1) * 32 + lg * 8)]);\
            acc[0][di_] = MFMA16(pa0, vf_, acc[0][di_]);                       \
            acc[1][di_] = MFMA16(pa1, vf_, acc[1][di_]);                       \
        }                                                                      \
        __builtin_amdgcn_s_setprio(0);                                         \
    } while (0)

    #define STEP(T_, KR, VR, KS, VS) do {                          \
        asm volatile("s_waitcnt vmcnt(4)" ::: "memory");           \
        __builtin_amdgcn_s_barrier();                              \
        asm volatile("" ::: "memory");                             \
        if ((T_) < 61) { STAGE2((T_) + 3, KS, VS); }               \
        COMPUTE(KR, VR);                                           \
    } while (0)

    // prologue: stage tiles 0,1,2 (6 loads in flight)
    STAGE2(0, Ks0, Vs0);
    STAGE2(1, Ks1, Vs1);
    STAGE2(2, Ks2, Vs2);

    for (int it = 0; it < 16; ++it) {
        const int t = it << 2;
        STEP(t + 0, Kb0, Vb0, Ks3, Vs3);
        STEP(t + 1, Kb1, Vb1, Ks0, Vs0);
        STEP(t + 2, Kb2, Vb2, Ks1, Vs1);
        STEP(t + 3, Kb3, Vb3, Ks2, Vs2);
    }
    #undef STEP
    #undef COMPUTE
    #undef STAGE2
    #undef MFMA16

    // ---- combine the two kv-halves: O = (O0+O1)/(l0+l1) ----
    __syncthreads();   // all K/V reads done; smem reusable as f32 exchange buffer
    float* xch = (float*)smem;
    const int xi = (wv * 64 + lane) * 44;   // 44 f32 stride: 16B-aligned, bank-spread
    if (wg == 1) {
        #pragma unroll
        for (int qi = 0; qi < 2; ++qi) {
            #pragma unroll
            for (int di = 0; di < 4; ++di)
                *(f32x4*)(xch + xi + qi * 16 + di * 4) = acc[qi][di];
            *(f32x4*)(xch + xi + 32 + qi * 4) = lacc[qi];
        }
    }
    __syncthreads();
    if (wg == 0) {
        #pragma unroll
        for (int qi = 0; qi < 2; ++qi) {
            #pragma unroll
            for (int di = 0; di < 4; ++di)
                acc[qi][di] += *(const f32x4*)(xch + xi + qi * 16 + di * 4);
            lacc[qi] += *(const f32x4*)(xch + xi + 32 + qi * 4);
        }
        #pragma unroll
        for (int qi = 0; qi < 2; ++qi) {
            float inv[4];
            #pragma unroll
            for (int r = 0; r < 4; ++r) inv[r] = 1.0f / lacc[qi][r];
            #pragma unroll
            for (int di = 0; di < 4; ++di) {
                const int e = di * 16 + l15;
                #pragma unroll
                for (int r = 0; r < 4; ++r) {
                    const int qn = q0 + wv * 32 + qi * 16 + lg * 4 + r;
                    ob[((size_t)(b * SEQ + qn) << 9) + h * 64 + e] = f2bf(acc[qi][di][r] * inv[r]);
                }
            }
        }
    }
}

// ---------------- proj GEMM (bf16 via gload_lds) + bias + residual: y = x + ao@w^T + bp
__global__ __launch_bounds__(256) void proj_k(
    const short* __restrict__ ao, const short* __restrict__ wpb,
    const float* __restrict__ bp, const float* __restrict__ x,
    float* __restrict__ y)
{
    __shared__ alignas(16) short As[2][128 * 64];
    __shared__ alignas(16) short Bs[2][128 * 64];
    const int tid  = threadIdx.x;
    const int lane = tid & 63;
    const int l15  = lane & 15;
    const int lg   = lane >> 4;
    const int wv   = tid >> 6;
    const int wy   = wv >> 1, wx = wv & 1;
    const int m0 = blockIdx.x * 128;
    const int n0 = blockIdx.y * 128;

    const f32x4 fzero = {0.f, 0.f, 0.f, 0.f};
    f32x4 acc[4][4];
    #pragma unroll
    for (int i = 0; i < 4; ++i)
        #pragma unroll
        for (int j = 0; j < 4; ++j)
            acc[i][j] = fzero;

    const int row0 = wv * 8 + (lane >> 3);
    const int cb   = ((lane & 7) ^ (lane >> 3)) << 4;
    const char* agp = (const char*)ao  + (size_t)(m0 + row0) * 1024 + cb;
    const char* bgp = (const char*)wpb + (size_t)(n0 + row0) * 1024 + cb;
    char* al0 = (char*)&As[0][0] + wv * 1024;
    char* al1 = (char*)&As[1][0] + wv * 1024;
    char* bl0 = (char*)&Bs[0][0] + wv * 1024;
    char* bl1 = (char*)&Bs[1][0] + wv * 1024;

    #define PSTAGE(al, bl, kofs) do {                                  \
        _Pragma("unroll")                                              \
        for (int i_ = 0; i_ < 4; ++i_) {                               \
            gl16(agp + (kofs) + i_ * 32768, (al) + i_ * 4096);         \
            gl16(bgp + (kofs) + i_ * 32768, (bl) + i_ * 4096);         \
        } } while (0)

    PSTAGE(al0, bl0, 0);

    int cur = 0;
    for (int k0 = 0; k0 < CDIM; k0 += 64) {
        asm volatile("s_waitcnt vmcnt(0)" ::: "memory");
        __syncthreads();
        if (k0 + 64 < CDIM) {
            if (cur == 0) PSTAGE(al1, bl1, (k0 + 64) * 2);
            else          PSTAGE(al0, bl0, (k0 + 64) * 2);
        }
        const short* Ac = cur ? &As[1][0] : &As[0][0];
        const short* Bc = cur ? &Bs[1][0] : &Bs[0][0];

        #pragma unroll
        for (int ks = 0; ks < 2; ++ks) {
            bf16x8 afr[4], bfr[4];
            #pragma unroll
            for (int i = 0; i < 4; ++i) {
                afr[i] = *(const bf16x8*)(&Ac[swz(wy * 64 + i * 16 + l15, ks * 32 + lg * 8)]);
                bfr[i] = *(const bf16x8*)(&Bc[swz(wx * 64 + i * 16 + l15, ks * 32 + lg * 8)]);
            }
            #pragma unroll
            for (int i = 0; i < 4; ++i)
                #pragma unroll
                for (int j = 0; j < 4; ++j)
                    acc[i][j] = __builtin_amdgcn_mfma_f32_16x16x32_bf16(afr[i], bfr[j], acc[i][j], 0, 0, 0);
        }
        cur ^= 1;
    }
    #undef PSTAGE

    #pragma unroll
    for (int i = 0; i < 4; ++i) {
        #pragma unroll
        for (int j = 0; j < 4; ++j) {
            const int d = n0 + wx * 64 + j * 16 + l15;
            #pragma unroll
            for (int r = 0; r < 4; ++r) {
                const int m = m0 + wy * 64 + i * 16 + lg * 4 + r;
                const size_t idx = (size_t)m * CDIM + d;
                y[idx] = acc[i][j][r] + bp[d] + x[idx];
            }
        }
    }
}

// ---------------- LayerNorm in place over d_out rows (512 f32 each), 1 wave/row
__global__ __launch_bounds__(256) void ln_k(
    float* __restrict__ y, const float* __restrict__ gm, const float* __restrict__ bt)
{
    const int lane = threadIdx.x & 63;
    const int row  = blockIdx.x * 4 + (threadIdx.x >> 6);
    float* p = y + (size_t)row * CDIM;
    float4 a = *(const float4*)(p + lane * 4);
    float4 b = *(const float4*)(p + 256 + lane * 4);
    float s = a.x + a.y + a.z + a.w + b.x + b.y + b.z + b.w;
    float q = a.x * a.x + a.y * a.y + a.z * a.z + a.w * a.w
            + b.x * b.x + b.y * b.y + b.z * b.z + b.w * b.w;
    #pragma unroll
    for (int mm = 1; mm < 64; mm <<= 1) {
        s += __shfl_xor(s, mm, 64);
        q += __shfl_xor(q, mm, 64);
    }
    const float mean = s * (1.0f / CDIM);
    const float var  = q * (1.0f / CDIM) - mean * mean;
    const float inv  = rsqrtf(var + 1e-5f);
    float4 g0 = *(const float4*)(gm + lane * 4);
    float4 g1 = *(const float4*)(gm + 256 + lane * 4);
    float4 t0 = *(const float4*)(bt + lane * 4);
    float4 t1 = *(const float4*)(bt + 256 + lane * 4);
    float4 r0, r1;
    r0.x = (a.x - mean) * inv * g0.x + t0.x;
    r0.y = (a.y - mean) * inv * g0.y + t0.y;
    r0.z = (a.z - mean) * inv * g0.z + t0.z;
    r0.w = (a.w - mean) * inv * g0.w + t0.w;
    r1.x = (b.x - mean) * inv * g1.x + t1.x;
    r1.y = (b.y - mean) * inv * g1.y + t1.y;
    r1.z = (b.z - mean) * inv * g1.z + t1.z;
    r1.w = (b.w - mean) * inv * g1.w + t1.w;
    *(float4*)(p + lane * 4) = r0;
    *(float4*)(p + 256 + lane * 4) = r1;
}

extern "C" void kernel_launch(void* const* d_in, const int* in_sizes, int n_in,
                              void* d_out, int out_size, void* d_ws, size_t ws_size,
                              hipStream_t stream)
{
    const float* x      = (const float*)d_in[0];
    const float* w_qkv  = (const float*)d_in[1];
    const float* w_proj = (const float*)d_in[2];
    const float* b_proj = (const float*)d_in[3];
    const float* gamma  = (const float*)d_in[4];
    const float* beta   = (const float*)d_in[5];
    float* out = (float*)d_out;

    const size_t qkv_elems = (size_t)16 * SEQ * HDIM;
    short* qb    = (short*)d_ws;
    short* kb    = qb + qkv_elems;
    short* vtb   = kb + qkv_elems;
    short* ob    = vtb + qkv_elems;
    short* xb    = ob;                     // alias: xb dead before attn writes ob
    short* wqkvb = ob + qkv_elems;
    short* wpb   = wqkvb + (size_t)3 * CDIM * CDIM;

    cvt3_k    <<<dim3(1024),   256, 0, stream>>>(
        x, xb, (2 * SEQ * CDIM) / 4,
        w_qkv, wqkvb, (3 * CDIM * CDIM) / 4,
        w_proj, wpb, (CDIM * CDIM) / 4);
    qkv_gemm_k<<<dim3(64, 12), 256, 0, stream>>>(xb, wqkvb, qb, kb, vtb);
    attn_k    <<<dim3(512),    512, 0, stream>>>(qb, kb, vtb, ob);
    proj_k    <<<dim3(64, 4),  256, 0, stream>>>(ob, wpb, b_proj, x, out);
    ln_k      <<<dim3(2048),   256, 0, stream>>>(out, gamma, beta);
}